// Round 13
// baseline (276.657 us; speedup 1.0000x reference)
//
#include <hip/hip_runtime.h>
#include <cstdint>
#include <cstddef>

typedef __bf16 bf16_t;
typedef __bf16 bf16x8 __attribute__((ext_vector_type(8)));
typedef __bf16 bf16x4v __attribute__((ext_vector_type(4)));
typedef float f32x16 __attribute__((ext_vector_type(16)));

static __device__ __forceinline__ f32x16 mfma32(bf16x8 a, bf16x8 b, f32x16 c) {
  return __builtin_amdgcn_mfma_f32_32x32x16_bf16(a, b, c, 0, 0, 0);
}

// Direct global->LDS DMA, 16B per lane (attn kernel only).
static __device__ __forceinline__ void gld_lds16(const void* g, void* l) {
  __builtin_amdgcn_global_load_lds(
      (const __attribute__((address_space(1))) unsigned int*)g,
      (__attribute__((address_space(3))) unsigned int*)l, 16, 0, 0);
}

#define CEXP_CONST 0.12754582f  // (1/sqrt(128)) * log2(e)

// ---------------------------------------------------------------------------
// Workspace layout (bytes):
//   [0, 768K)        Wt2   bf16 [3][64 k16][4 nf][2 h][32 l31][8]  (frag-major)
//   [1M, 9M)         Qp    bf16 [8][4096][128]
//   [9M, 17M)        Kp    bf16 [8][4096][128]
//   [17M, 25M)       Vt    bf16 [8][128][4096]
//   [32M, 64M)       Opart f32  [2*256][128][128]
//   [64M, +256K)     Mpart f32  [2*256*128]
//   [64M+256K,+256K) Lpart f32  [2*256*128]
// ---------------------------------------------------------------------------

// W -> fragment-major bf16: Wt2[((k16*4+nf)*2+h)*32+l31][j] = W[k16*16+h*8+j][nf*32+l31]
__global__ void wt_kernel(const float* __restrict__ Wq, const float* __restrict__ Wk,
                          const float* __restrict__ Wv, bf16_t* __restrict__ Wt2) {
  int t = blockIdx.x * 256 + threadIdx.x;   // 0..393215
  int tensor = t >> 17;
  int r = t & 131071;
  int j = r & 7, l31 = (r >> 3) & 31, h = (r >> 8) & 1, nf = (r >> 9) & 3, k16 = (r >> 11) & 63;
  int k = k16 * 16 + h * 8 + j, n = nf * 32 + l31;
  const float* W = tensor == 0 ? Wq : (tensor == 1 ? Wk : Wv);
  Wt2[t] = (bf16_t)W[(size_t)k * 128 + n];
}

// X[32768,1024]f32 @ W[1024,128] -> bf16.  BM=64, BK=64, 16 phases, 3 blocks/CU.
// R13: W SHARED VIA LDS (4x less W traffic than per-wave register fragments).
// Per phase the block stages A (16KB f32 -> 8KB bf16 swizzled) AND the W
// phase-slice (16KB linear copy of frag-major Wt2). Single barrier per phase,
// both tiles double-buffered, one S-register set loaded 2 phases ahead (R12).
// Wave w = (mh = w&1, nh = w>>1): computes 32m x 64n -> 2 accumulators.
// ty: 0=Q, 1=K (row-major out), 2=V (transposed out).
__global__ __launch_bounds__(256, 3) void proj_kernel(
    const float* __restrict__ xq, const float* __restrict__ xk, const float* __restrict__ xv,
    const bf16_t* __restrict__ WtAll,
    bf16_t* __restrict__ Qp, bf16_t* __restrict__ Kp, bf16_t* __restrict__ Vt) {
  // A dbuf [0,16K): 2 x 8KB [64 rows][128B] swizzled.
  // W dbuf [16K,48K): 2 x 16KB linear frag-major phase slice.
  // Epilogue reuses [0,17.5K).
  __shared__ __align__(16) char smc[49152];
  const int tid = threadIdx.x;
  const int ty = blockIdx.y;
  const int bm = blockIdx.x;               // 0..511 (64-row blocks)
  const float* X = (ty == 0) ? xq : (ty == 1) ? xk : xv;
  const bf16_t* W2 = WtAll + (size_t)ty * 131072;
  const int lane = tid & 63;
  const int w = tid >> 6;
  const int l31 = lane & 31, h = lane >> 5;
  const int mh = w & 1, nh = w >> 1;

  const char* aG = (const char*)X + (size_t)bm * 262144;   // 64 rows x 4KB
  const char* wG = (const char*)W2;                        // phase p at p*16384

  float4 SX[4];
  uint4 SW[4];
  auto ldg = [&](int p) {
#pragma unroll
    for (int i = 0; i < 4; ++i) {
      int c = i * 256 + tid;
      SX[i] = *(const float4*)(aG + (size_t)(c >> 4) * 4096 + p * 256 + (c & 15) * 16);
    }
#pragma unroll
    for (int i = 0; i < 4; ++i)
      SW[i] = *(const uint4*)(wG + p * 16384 + (i * 256 + tid) * 16);
  };
  auto stg = [&](int buf) {
#pragma unroll
    for (int i = 0; i < 4; ++i) {
      int c = i * 256 + tid;
      int row = c >> 4, s = c & 15;
      bf16x4v bv;
      bv[0] = (bf16_t)SX[i].x; bv[1] = (bf16_t)SX[i].y;
      bv[2] = (bf16_t)SX[i].z; bv[3] = (bf16_t)SX[i].w;
      int dst = buf * 8192 + row * 128 + (((s >> 1) ^ (row & 7)) << 4) + (s & 1) * 8;
      *(uint2*)(smc + dst) = __builtin_bit_cast(uint2, bv);
    }
#pragma unroll
    for (int i = 0; i < 4; ++i)
      *(uint4*)(smc + 16384 + buf * 16384 + (i * 256 + tid) * 16) = SW[i];
  };

  f32x16 acc0, acc1;
#pragma unroll
  for (int r = 0; r < 16; ++r) { acc0[r] = 0.0f; acc1[r] = 0.0f; }
  const int asw = l31 & 7;

  auto kloop = [&](int buf) {
    const char* ab = smc + buf * 8192 + (mh * 32 + l31) * 128;
    const char* wb = smc + 16384 + buf * 16384 + h * 512 + l31 * 16;
#pragma unroll
    for (int k = 0; k < 4; ++k) {
      bf16x8 af = *(const bf16x8*)(ab + (((2 * k + h) ^ asw) << 4));
      bf16x8 wf0 = *(const bf16x8*)(wb + (k * 4 + nh * 2 + 0) * 1024);
      bf16x8 wf1 = *(const bf16x8*)(wb + (k * 4 + nh * 2 + 1) * 1024);
      acc0 = mfma32(af, wf0, acc0);
      acc1 = mfma32(af, wf1, acc1);
    }
  };

  // prologue: data(0) -> buf0; S <- data(1)
  ldg(0);
  stg(0);
  ldg(1);
  __syncthreads();

#pragma unroll 2
  for (int p = 0; p < 16; ++p) {
    kloop(p & 1);
    if (p + 1 < 16) stg((p + 1) & 1);   // writes the buffer nobody reads now
    if (p + 2 < 16) ldg(p + 2);
    __syncthreads();
  }

  // C/D map: col = nb*32 + l31, row = mh*32 + (r&3) + 8*(r>>2) + 4*h.
  if (ty < 2) {
    constexpr int RS = 264;
#pragma unroll
    for (int r = 0; r < 16; ++r) {
      int m = mh * 32 + (r & 3) + 8 * (r >> 2) + 4 * h;
      *(bf16_t*)(smc + m * RS + ((nh * 2 + 0) * 32 + l31) * 2) = (bf16_t)acc0[r];
      *(bf16_t*)(smc + m * RS + ((nh * 2 + 1) * 32 + l31) * 2) = (bf16_t)acc1[r];
    }
    __syncthreads();
    bf16_t* O = (ty == 0) ? Qp : Kp;
    char* obase = (char*)O + (size_t)bm * 16384;
#pragma unroll
    for (int i = 0; i < 4; ++i) {
      int c = i * 256 + tid;           // 1024 x 16B chunks
      int rr = c >> 4, ch = c & 15;
      uint4 vv = *(const uint4*)(smc + rr * RS + ch * 16);
      *(uint4*)(obase + rr * 256 + ch * 16) = vv;
    }
  } else {
    // transpose: stage [128 n][136B pad], write Vt[b][n][m] in 16B chunks
#pragma unroll
    for (int r = 0; r < 16; ++r) {
      int m = mh * 32 + (r & 3) + 8 * (r >> 2) + 4 * h;
      *(bf16_t*)(smc + ((nh * 2 + 0) * 32 + l31) * 136 + m * 2) = (bf16_t)acc0[r];
      *(bf16_t*)(smc + ((nh * 2 + 1) * 32 + l31) * 136 + m * 2) = (bf16_t)acc1[r];
    }
    __syncthreads();
    const int bb = bm >> 6;            // batch (64 blocks per batch)
    const int m0b = (bm & 63) * 128;   // byte offset of m-slice within row
#pragma unroll
    for (int i = 0; i < 4; ++i) {
      int c = i * 256 + tid;           // 1024 x 16B chunks
      int n = c >> 3, s = c & 7;
      uint4 vv = *(const uint4*)(smc + n * 136 + s * 16);
      *(uint4*)((char*)Vt + (size_t)bb * 1048576 + (size_t)n * 8192 + m0b + s * 16) = vv;
    }
  }
}

// Build PV A-fragment in-register: 4x v_cvt_pk_bf16_f32 + 4x shfl_xor(32).
template <int B0>
static __device__ __forceinline__ bf16x8 build_pf(const f32x16& s, int h) {
  unsigned c0, c1, c2, c3;
  asm("v_cvt_pk_bf16_f32 %0, %1, %2" : "=v"(c0) : "v"(s[B0 + 0]), "v"(s[B0 + 1]));
  asm("v_cvt_pk_bf16_f32 %0, %1, %2" : "=v"(c1) : "v"(s[B0 + 2]), "v"(s[B0 + 3]));
  asm("v_cvt_pk_bf16_f32 %0, %1, %2" : "=v"(c2) : "v"(s[B0 + 4]), "v"(s[B0 + 5]));
  asm("v_cvt_pk_bf16_f32 %0, %1, %2" : "=v"(c3) : "v"(s[B0 + 6]), "v"(s[B0 + 7]));
  unsigned x0 = (unsigned)__shfl_xor((int)c0, 32);
  unsigned x1 = (unsigned)__shfl_xor((int)c1, 32);
  unsigned x2 = (unsigned)__shfl_xor((int)c2, 32);
  unsigned x3 = (unsigned)__shfl_xor((int)c3, 32);
  uint4 u;
  u.x = h ? x2 : c0;
  u.y = h ? x3 : c1;
  u.z = h ? c2 : x0;
  u.w = h ? c3 : x1;
  return __builtin_bit_cast(bf16x8, u);
}

// Flash attention (unchanged: gld_lds dbuf, counted vmcnt(8)).
template <int SPLIT>
__global__ __launch_bounds__(256, 2) void attn_kernel(
    const bf16_t* __restrict__ Qp, const bf16_t* __restrict__ Kp,
    const bf16_t* __restrict__ Vt, float* __restrict__ out,
    float* __restrict__ Opart, float* __restrict__ Mpart, float* __restrict__ Lpart) {
  __shared__ __align__(16) char smc[65536];  // 2 x (K 16K | V 16K)
  const int tid = threadIdx.x;
  const int lane = tid & 63, w = tid >> 6;
  const int l31 = lane & 31, h = lane >> 5;
  const int bid = blockIdx.x;
  const int b = bid & 7;
  const int qt = (bid >> 3) & 31;
  const int s = bid >> 8;
  const int NT = 64 / SPLIT;
  const float CEXP = CEXP_CONST;
  const int qbase = qt * 128 + w * 32;
  const int sw0 = (l31 ^ (l31 >> 3)) & 7;
  const int sw1 = sw0 ^ 4;

  bf16x8 qf[8];
  const bf16_t* qrow = Qp + (size_t)(b * 4096 + qbase + l31) * 128 + h * 8;
#pragma unroll
  for (int db = 0; db < 8; ++db) qf[db] = *(const bf16x8*)(qrow + db * 16);

  int swv[4];
#pragma unroll
  for (int nf = 0; nf < 4; ++nf) swv[nf] = (l31 & 7) ^ ((4 * nf + (l31 >> 3)) & 7);

  const int rl = lane >> 4, slK = lane & 15;
  const int dl = lane >> 3, slV = lane & 7;
  int koff[4], voff[4];
#pragma unroll
  for (int i = 0; i < 4; ++i) {
    int r = w * 16 + i * 4 + rl;
    int swr = (r ^ (r >> 3)) & 7;
    koff[i] = r * 256 + (((slK & 8) | ((slK & 7) ^ swr)) << 4);
    int d = w * 32 + i * 8 + dl;
    int swd = (d ^ (d >> 3)) & 7;
    voff[i] = d * 8192 + ((slV ^ swd) << 4);
  }
  const char* kpb = (const char*)Kp + (size_t)b * 1048576 + (size_t)s * NT * 16384;
  const char* vpb = (const char*)Vt + (size_t)b * 1048576 + (size_t)s * NT * 128;

  f32x16 oacc[4];
#pragma unroll
  for (int nf = 0; nf < 4; ++nf)
#pragma unroll
    for (int r = 0; r < 16; ++r) oacc[nf][r] = 0.0f;
  float m_run = -3.0e38f, lacc = 0.0f;

  auto stage = [&](int tt, int bufb) {
    const char* kb = kpb + (size_t)tt * 16384;
    const char* vb = vpb + (size_t)tt * 128;
    char* lk = smc + bufb + w * 4096;
    char* lv = smc + bufb + 16384 + w * 4096;
#pragma unroll
    for (int i = 0; i < 4; ++i) {
      gld_lds16(kb + koff[i], lk + i * 1024);
      gld_lds16(vb + voff[i], lv + i * 1024);
    }
  };

  stage(0, 0);
  stage(1, 32768);

  for (int t = 0; t < NT; ++t) {
    asm volatile("s_waitcnt vmcnt(8)" ::: "memory");
    __builtin_amdgcn_s_barrier();
    const char* kb = smc + (t & 1) * 32768;
    const char* vb = kb + 16384;

    f32x16 s0, s1;
#pragma unroll
    for (int i = 0; i < 16; ++i) { s0[i] = 0.0f; s1[i] = 0.0f; }
    __builtin_amdgcn_s_setprio(1);
#pragma unroll
    for (int db = 0; db < 8; ++db) {
      const int q = 2 * db + h;
      bf16x8 k0 = *(const bf16x8*)(kb + l31 * 256 + (((q & 8) | ((q & 7) ^ sw0)) << 4));
      bf16x8 k1 = *(const bf16x8*)(kb + (32 + l31) * 256 + (((q & 8) | ((q & 7) ^ sw1)) << 4));
      s0 = mfma32(k0, qf[db], s0);
      s1 = mfma32(k1, qf[db], s1);
    }
    __builtin_amdgcn_s_setprio(0);

    float tmax = fmaxf(s0[0], s1[0]);
#pragma unroll
    for (int i = 1; i < 16; ++i) tmax = fmaxf(tmax, fmaxf(s0[i], s1[i]));
    tmax = fmaxf(tmax, __shfl_xor(tmax, 32));
    if (__any(tmax > m_run + 62.0f)) {
      float mnew = fmaxf(m_run, tmax);
      float fac = exp2f((m_run - mnew) * CEXP);
      m_run = mnew;
      lacc *= fac;
#pragma unroll
      for (int r = 0; r < 16; ++r) {
        float fr = __shfl(fac, (r & 3) + 8 * (r >> 2) + 4 * h);
#pragma unroll
        for (int nf = 0; nf < 4; ++nf) oacc[nf][r] *= fr;
      }
    }
    const float mc = m_run * CEXP;
#pragma unroll
    for (int i = 0; i < 16; ++i) s0[i] = exp2f(fmaf(s0[i], CEXP, -mc));
#pragma unroll
    for (int i = 0; i < 16; ++i) s1[i] = exp2f(fmaf(s1[i], CEXP, -mc));
    float a0 = 0.f, a1 = 0.f, a2 = 0.f, a3 = 0.f;
#pragma unroll
    for (int i = 0; i < 16; i += 4) {
      a0 += s0[i] + s1[i];         a1 += s0[i + 1] + s1[i + 1];
      a2 += s0[i + 2] + s1[i + 2]; a3 += s0[i + 3] + s1[i + 3];
    }
    lacc += (a0 + a1) + (a2 + a3);

    __builtin_amdgcn_s_setprio(1);
    {
      bf16x8 pf = build_pf<0>(s0, h);
#pragma unroll
      for (int nf = 0; nf < 4; ++nf) {
        bf16x8 vf = *(const bf16x8*)(vb + (nf * 32 + l31) * 128 + (((0 + h) ^ swv[nf]) << 4));
        oacc[nf] = mfma32(pf, vf, oacc[nf]);
      }
    }
    {
      bf16x8 pf = build_pf<8>(s0, h);
#pragma unroll
      for (int nf = 0; nf < 4; ++nf) {
        bf16x8 vf = *(const bf16x8*)(vb + (nf * 32 + l31) * 128 + (((2 + h) ^ swv[nf]) << 4));
        oacc[nf] = mfma32(pf, vf, oacc[nf]);
      }
    }
    {
      bf16x8 pf = build_pf<0>(s1, h);
#pragma unroll
      for (int nf = 0; nf < 4; ++nf) {
        bf16x8 vf = *(const bf16x8*)(vb + (nf * 32 + l31) * 128 + (((4 + h) ^ swv[nf]) << 4));
        oacc[nf] = mfma32(pf, vf, oacc[nf]);
      }
    }
    {
      bf16x8 pf = build_pf<8>(s1, h);
#pragma unroll
      for (int nf = 0; nf < 4; ++nf) {
        bf16x8 vf = *(const bf16x8*)(vb + (nf * 32 + l31) * 128 + (((6 + h) ^ swv[nf]) << 4));
        oacc[nf] = mfma32(pf, vf, oacc[nf]);
      }
    }
    __builtin_amdgcn_s_setprio(0);

    __builtin_amdgcn_s_barrier();
    stage((t + 2) & (NT - 1), (t & 1) * 32768);
  }
  asm volatile("s_waitcnt vmcnt(0)" ::: "memory");

  lacc += __shfl_xor(lacc, 32);
  if (SPLIT == 1) {
    const float inv = 1.0f / lacc;
    float* ob = out + (size_t)(b * 4096 + qbase) * 128;
#pragma unroll
    for (int r = 0; r < 16; ++r) {
      const int rowD = (r & 3) + 8 * (r >> 2) + 4 * h;
      float ir = __shfl(inv, rowD);
#pragma unroll
      for (int nf = 0; nf < 4; ++nf)
        ob[(size_t)rowD * 128 + nf * 32 + l31] = oacc[nf][r] * ir;
    }
  } else {
    const int pb = s * 256 + b * 32 + qt;
    if (lane < 32) {
      Mpart[pb * 128 + w * 32 + l31] = m_run;
      Lpart[pb * 128 + w * 32 + l31] = lacc;
    }
    float* ob = Opart + ((size_t)pb * 128 + w * 32) * 128;
#pragma unroll
    for (int r = 0; r < 16; ++r) {
      const int rowD = (r & 3) + 8 * (r >> 2) + 4 * h;
#pragma unroll
      for (int nf = 0; nf < 4; ++nf)
        ob[(size_t)rowD * 128 + nf * 32 + l31] = oacc[nf][r];
    }
  }
}

// Combine 2 split partials. grid 4096 x 256: 8 rows/block, 32 lanes/row (float4).
__global__ __launch_bounds__(256) void combine_kernel(
    const float* __restrict__ Opart, const float* __restrict__ Mpart,
    const float* __restrict__ Lpart, float* __restrict__ out) {
  const int g = blockIdx.x * 8 + (threadIdx.x >> 5);
  const int lane32 = threadIdx.x & 31;
  const int b = g >> 12;
  const int pos = g & 4095;
  const int qt = pos >> 7;
  const int row = pos & 127;
  const int i0 = (b * 32 + qt) * 128 + row;
  const int i1 = (256 + b * 32 + qt) * 128 + row;
  const float m0 = Mpart[i0], m1 = Mpart[i1];
  const float l0 = Lpart[i0], l1 = Lpart[i1];
  const float m = fmaxf(m0, m1);
  const float w0 = exp2f((m0 - m) * CEXP_CONST);
  const float w1 = exp2f((m1 - m) * CEXP_CONST);
  const float inv = 1.0f / (w0 * l0 + w1 * l1);
  const float4 o0 = *(const float4*)(Opart + (size_t)i0 * 128 + lane32 * 4);
  const float4 o1 = *(const float4*)(Opart + (size_t)i1 * 128 + lane32 * 4);
  float4 o;
  o.x = (w0 * o0.x + w1 * o1.x) * inv;
  o.y = (w0 * o0.y + w1 * o1.y) * inv;
  o.z = (w0 * o0.z + w1 * o1.z) * inv;
  o.w = (w0 * o0.w + w1 * o1.w) * inv;
  *(float4*)(out + (size_t)g * 128 + lane32 * 4) = o;
}

extern "C" void kernel_launch(void* const* d_in, const int* in_sizes, int n_in,
                              void* d_out, int out_size, void* d_ws, size_t ws_size,
                              hipStream_t stream) {
  const float* q  = (const float*)d_in[0];
  const float* k  = (const float*)d_in[1];
  const float* v  = (const float*)d_in[2];
  const float* Wq = (const float*)d_in[3];
  const float* Wk = (const float*)d_in[4];
  const float* Wv = (const float*)d_in[5];
  float* out = (float*)d_out;
  char* ws = (char*)d_ws;
  bf16_t* Wt2 = (bf16_t*)(ws);
  bf16_t* Qp = (bf16_t*)(ws + (size_t)(1u << 20));
  bf16_t* Kp = (bf16_t*)(ws + (size_t)(9u << 20));
  bf16_t* Vt = (bf16_t*)(ws + (size_t)(17u << 20));
  float* Opart = (float*)(ws + (size_t)(32u << 20));
  float* Mpart = (float*)(ws + (size_t)(64u << 20));
  float* Lpart = (float*)(ws + (size_t)(64u << 20) + (256u << 10));

  hipLaunchKernelGGL(wt_kernel, dim3(1536), dim3(256), 0, stream, Wq, Wk, Wv, Wt2);
  hipLaunchKernelGGL(proj_kernel, dim3(512, 3), dim3(256), 0, stream, q, k, v, Wt2, Qp, Kp, Vt);

  if (ws_size >= ((size_t)65 << 20)) {
    hipLaunchKernelGGL((attn_kernel<2>), dim3(512), dim3(256), 0, stream,
                       Qp, Kp, Vt, out, Opart, Mpart, Lpart);
    hipLaunchKernelGGL(combine_kernel, dim3(4096), dim3(256), 0, stream,
                       Opart, Mpart, Lpart, out);
  } else {
    hipLaunchKernelGGL((attn_kernel<1>), dim3(256), dim3(256), 0, stream,
                       Qp, Kp, Vt, out, Opart, Mpart, Lpart);
  }
}

// Round 14
// 206.607 us; speedup vs baseline: 1.3390x; 1.3390x over previous
//
#include <hip/hip_runtime.h>
#include <cstdint>
#include <cstddef>

typedef __bf16 bf16_t;
typedef __bf16 bf16x8 __attribute__((ext_vector_type(8)));
typedef __bf16 bf16x4v __attribute__((ext_vector_type(4)));
typedef float f32x16 __attribute__((ext_vector_type(16)));

static __device__ __forceinline__ f32x16 mfma32(bf16x8 a, bf16x8 b, f32x16 c) {
  return __builtin_amdgcn_mfma_f32_32x32x16_bf16(a, b, c, 0, 0, 0);
}

// Direct global->LDS DMA, 16B per lane (attn kernel only).
static __device__ __forceinline__ void gld_lds16(const void* g, void* l) {
  __builtin_amdgcn_global_load_lds(
      (const __attribute__((address_space(1))) unsigned int*)g,
      (__attribute__((address_space(3))) unsigned int*)l, 16, 0, 0);
}

#define CEXP_CONST 0.12754582f  // (1/sqrt(128)) * log2(e)

// ---------------------------------------------------------------------------
// Workspace layout (bytes):
//   [0, 768K)        Wt2   bf16 [3][64 k16][4 nf][2 h][32 l31][8]  (frag-major)
//   [1M, 9M)         Qp    bf16 [8][4096][128]
//   [9M, 17M)        Kp    bf16 [8][4096][128]
//   [17M, 25M)       Vt    bf16 [8][128][4096]
//   [32M, 64M)       Opart f32  [2*256][128][128]
//   [64M, +256K)     Mpart f32  [2*256*128]
//   [64M+256K,+256K) Lpart f32  [2*256*128]
// ---------------------------------------------------------------------------

// W -> fragment-major bf16: Wt2[((k16*4+nf)*2+h)*32+l31][j] = W[k16*16+h*8+j][nf*32+l31]
__global__ void wt_kernel(const float* __restrict__ Wq, const float* __restrict__ Wk,
                          const float* __restrict__ Wv, bf16_t* __restrict__ Wt2) {
  int t = blockIdx.x * 256 + threadIdx.x;   // 0..393215
  int tensor = t >> 17;
  int r = t & 131071;
  int j = r & 7, l31 = (r >> 3) & 31, h = (r >> 8) & 1, nf = (r >> 9) & 3, k16 = (r >> 11) & 63;
  int k = k16 * 16 + h * 8 + j, n = nf * 32 + l31;
  const float* W = tensor == 0 ? Wq : (tensor == 1 ? Wk : Wv);
  Wt2[t] = (bf16_t)W[(size_t)k * 128 + n];
}

// X[32768,1024]f32 @ W[1024,128] -> bf16.  BM=32, 8 K-phases, 4 blocks/CU.
// R12 (best verified): W(p+1) register-prefetched (wA/wB alternation, static
// indexing) so the per-phase L2 W-load latency is off the MFMA critical path;
// ONE barrier per phase (double-buffered A-LDS makes the pre-write barrier
// redundant). X staged via single S[4] register set, linear-ascending reads.
// ty: 0=Q, 1=K (row-major out), 2=V (transposed out).
__global__ __launch_bounds__(256, 4) void proj_kernel(
    const float* __restrict__ xq, const float* __restrict__ xk, const float* __restrict__ xv,
    const bf16_t* __restrict__ WtAll,
    bf16_t* __restrict__ Qp, bf16_t* __restrict__ Kp, bf16_t* __restrict__ Vt) {
  __shared__ __align__(16) char smc[16384];  // 2 x 8KB A-buf; epilogue reuses
  const int tid = threadIdx.x;
  const int ty = blockIdx.y;
  const int bm = blockIdx.x;               // 0..1023 (32-row blocks)
  const float* X = (ty == 0) ? xq : (ty == 1) ? xk : xv;
  const bf16_t* W2 = WtAll + (size_t)ty * 131072;
  const int lane = tid & 63;
  const int w = tid >> 6;
  const int l31 = lane & 31, h = lane >> 5;

  const char* aG = (const char*)X + (size_t)bm * 131072;

  // Phase p covers k in [p*128, (p+1)*128). 512 chunks of 16B f32;
  // chunk c: row = c>>5, slot s = c&31. LDS bf16 row stride 256B:
  // dst granule (s>>1) ^ (row&7), half s&1.
  float4 S[4];
  auto ldg = [&](int p) {
#pragma unroll
    for (int i = 0; i < 4; ++i) {
      int c = i * 256 + tid;
      S[i] = *(const float4*)(aG + (size_t)(c >> 5) * 4096 + p * 512 + (c & 31) * 16);
    }
  };
  auto stg = [&](int buf) {
#pragma unroll
    for (int i = 0; i < 4; ++i) {
      int c = i * 256 + tid;
      int row = c >> 5, s = c & 31;
      bf16x4v bv;
      bv[0] = (bf16_t)S[i].x; bv[1] = (bf16_t)S[i].y;
      bv[2] = (bf16_t)S[i].z; bv[3] = (bf16_t)S[i].w;
      int dst = buf * 8192 + row * 256 + ((((s >> 1) ^ (row & 7)) << 4)) + (s & 1) * 8;
      *(uint2*)(smc + dst) = __builtin_bit_cast(uint2, bv);
    }
  };

  bf16x8 wA[8], wB[8];
  const bf16_t* wbase = W2 + w * 512 + lane * 8;
  auto ldw = [&](bf16x8 (&Wf)[8], int p) {
#pragma unroll
    for (int kk = 0; kk < 8; ++kk)
      Wf[kk] = *(const bf16x8*)(wbase + (size_t)(p * 8 + kk) * 2048);
  };

  f32x16 acc;
#pragma unroll
  for (int r = 0; r < 16; ++r) acc[r] = 0.0f;
  const int asw = l31 & 7;
  auto kloop = [&](bf16x8 (&Wf)[8], int buf) {
    const char* arow = smc + buf * 8192 + l31 * 256;
#pragma unroll
    for (int kk = 0; kk < 8; ++kk) {
      bf16x8 af = *(const bf16x8*)(arow + (((kk * 2 + h) ^ asw) << 4));
      acc = mfma32(af, Wf[kk], acc);
    }
  };

  // prologue: data(0) -> buf0; S <- data(1); wA <- W(0)
  ldg(0);
  stg(0);
  ldg(1);
  ldw(wA, 0);
  __syncthreads();

#pragma unroll
  for (int p2 = 0; p2 < 4; ++p2) {
    const int pe = 2 * p2;
    // even phase pe: compute with wA (buf0), prefetch wB <- W(pe+1)
    ldw(wB, pe + 1);
    kloop(wA, 0);
    stg(1);                       // data(pe+1) -> buf1 (nobody reads buf1 now)
    if (pe + 2 < 8) ldg(pe + 2);  // issue X two phases ahead
    __syncthreads();
    // odd phase po = pe+1: compute with wB (buf1), prefetch wA <- W(po+1)
    const int po = pe + 1;
    if (po + 1 < 8) ldw(wA, po + 1);
    kloop(wB, 1);
    if (po + 1 < 8) {
      stg(0);                     // data(po+1) -> buf0
      if (po + 2 < 8) ldg(po + 2);
    }
    __syncthreads();
  }
  // smc reused below (last barrier above protects it)

  // C/D map: col n = w*32 + l31, row m = (r&3) + 8*(r>>2) + 4*h.
  if (ty < 2) {
    constexpr int RS = 264;
#pragma unroll
    for (int r = 0; r < 16; ++r) {
      int m = (r & 3) + 8 * (r >> 2) + 4 * h;
      *(bf16_t*)(smc + m * RS + (w * 32 + l31) * 2) = (bf16_t)acc[r];
    }
    __syncthreads();
    bf16_t* O = (ty == 0) ? Qp : Kp;
    char* obase = (char*)O + (size_t)bm * 8192;
#pragma unroll
    for (int i = 0; i < 2; ++i) {
      int c = i * 256 + tid;           // 512 x 16B chunks
      int rr = c >> 4, ch = c & 15;
      uint4 vv = *(const uint4*)(smc + rr * RS + ch * 16);
      *(uint4*)(obase + rr * 256 + ch * 16) = vv;
    }
  } else {
    // transpose: stage [128 n][72B pad], write Vt[b][n][m] in 32B chunks
#pragma unroll
    for (int q = 0; q < 4; ++q) {
      int n = w * 32 + l31;
      bf16x4v bv;
#pragma unroll
      for (int j = 0; j < 4; ++j) bv[j] = (bf16_t)acc[q * 4 + j];
      *(uint2*)(smc + n * 72 + q * 16 + h * 8) = __builtin_bit_cast(uint2, bv);
    }
    __syncthreads();
    const int bb = bm >> 7;            // batch
    const int m0 = (bm & 127) * 32;    // m offset within batch
    {
      int n = tid >> 1, half = tid & 1;
      const char* src = smc + n * 72 + half * 32;
      char* dst = (char*)Vt + (size_t)bb * 1048576 + (size_t)n * 8192 + m0 * 2 + half * 32;
      uint4 v0 = *(const uint4*)(src);
      uint4 v1 = *(const uint4*)(src + 16);
      *(uint4*)(dst) = v0;
      *(uint4*)(dst + 16) = v1;
    }
  }
}

// Build PV A-fragment in-register: 4x v_cvt_pk_bf16_f32 + 4x shfl_xor(32).
template <int B0>
static __device__ __forceinline__ bf16x8 build_pf(const f32x16& s, int h) {
  unsigned c0, c1, c2, c3;
  asm("v_cvt_pk_bf16_f32 %0, %1, %2" : "=v"(c0) : "v"(s[B0 + 0]), "v"(s[B0 + 1]));
  asm("v_cvt_pk_bf16_f32 %0, %1, %2" : "=v"(c1) : "v"(s[B0 + 2]), "v"(s[B0 + 3]));
  asm("v_cvt_pk_bf16_f32 %0, %1, %2" : "=v"(c2) : "v"(s[B0 + 4]), "v"(s[B0 + 5]));
  asm("v_cvt_pk_bf16_f32 %0, %1, %2" : "=v"(c3) : "v"(s[B0 + 6]), "v"(s[B0 + 7]));
  unsigned x0 = (unsigned)__shfl_xor((int)c0, 32);
  unsigned x1 = (unsigned)__shfl_xor((int)c1, 32);
  unsigned x2 = (unsigned)__shfl_xor((int)c2, 32);
  unsigned x3 = (unsigned)__shfl_xor((int)c3, 32);
  uint4 u;
  u.x = h ? x2 : c0;
  u.y = h ? x3 : c1;
  u.z = h ? c2 : x0;
  u.w = h ? c3 : x1;
  return __builtin_bit_cast(bf16x8, u);
}

// Flash attention (unchanged: gld_lds dbuf, counted vmcnt(8)).
template <int SPLIT>
__global__ __launch_bounds__(256, 2) void attn_kernel(
    const bf16_t* __restrict__ Qp, const bf16_t* __restrict__ Kp,
    const bf16_t* __restrict__ Vt, float* __restrict__ out,
    float* __restrict__ Opart, float* __restrict__ Mpart, float* __restrict__ Lpart) {
  __shared__ __align__(16) char smc[65536];  // 2 x (K 16K | V 16K)
  const int tid = threadIdx.x;
  const int lane = tid & 63, w = tid >> 6;
  const int l31 = lane & 31, h = lane >> 5;
  const int bid = blockIdx.x;
  const int b = bid & 7;
  const int qt = (bid >> 3) & 31;
  const int s = bid >> 8;
  const int NT = 64 / SPLIT;
  const float CEXP = CEXP_CONST;
  const int qbase = qt * 128 + w * 32;
  const int sw0 = (l31 ^ (l31 >> 3)) & 7;
  const int sw1 = sw0 ^ 4;

  bf16x8 qf[8];
  const bf16_t* qrow = Qp + (size_t)(b * 4096 + qbase + l31) * 128 + h * 8;
#pragma unroll
  for (int db = 0; db < 8; ++db) qf[db] = *(const bf16x8*)(qrow + db * 16);

  int swv[4];
#pragma unroll
  for (int nf = 0; nf < 4; ++nf) swv[nf] = (l31 & 7) ^ ((4 * nf + (l31 >> 3)) & 7);

  const int rl = lane >> 4, slK = lane & 15;
  const int dl = lane >> 3, slV = lane & 7;
  int koff[4], voff[4];
#pragma unroll
  for (int i = 0; i < 4; ++i) {
    int r = w * 16 + i * 4 + rl;
    int swr = (r ^ (r >> 3)) & 7;
    koff[i] = r * 256 + (((slK & 8) | ((slK & 7) ^ swr)) << 4);
    int d = w * 32 + i * 8 + dl;
    int swd = (d ^ (d >> 3)) & 7;
    voff[i] = d * 8192 + ((slV ^ swd) << 4);
  }
  const char* kpb = (const char*)Kp + (size_t)b * 1048576 + (size_t)s * NT * 16384;
  const char* vpb = (const char*)Vt + (size_t)b * 1048576 + (size_t)s * NT * 128;

  f32x16 oacc[4];
#pragma unroll
  for (int nf = 0; nf < 4; ++nf)
#pragma unroll
    for (int r = 0; r < 16; ++r) oacc[nf][r] = 0.0f;
  float m_run = -3.0e38f, lacc = 0.0f;

  auto stage = [&](int tt, int bufb) {
    const char* kb = kpb + (size_t)tt * 16384;
    const char* vb = vpb + (size_t)tt * 128;
    char* lk = smc + bufb + w * 4096;
    char* lv = smc + bufb + 16384 + w * 4096;
#pragma unroll
    for (int i = 0; i < 4; ++i) {
      gld_lds16(kb + koff[i], lk + i * 1024);
      gld_lds16(vb + voff[i], lv + i * 1024);
    }
  };

  stage(0, 0);
  stage(1, 32768);

  for (int t = 0; t < NT; ++t) {
    asm volatile("s_waitcnt vmcnt(8)" ::: "memory");
    __builtin_amdgcn_s_barrier();
    const char* kb = smc + (t & 1) * 32768;
    const char* vb = kb + 16384;

    f32x16 s0, s1;
#pragma unroll
    for (int i = 0; i < 16; ++i) { s0[i] = 0.0f; s1[i] = 0.0f; }
    __builtin_amdgcn_s_setprio(1);
#pragma unroll
    for (int db = 0; db < 8; ++db) {
      const int q = 2 * db + h;
      bf16x8 k0 = *(const bf16x8*)(kb + l31 * 256 + (((q & 8) | ((q & 7) ^ sw0)) << 4));
      bf16x8 k1 = *(const bf16x8*)(kb + (32 + l31) * 256 + (((q & 8) | ((q & 7) ^ sw1)) << 4));
      s0 = mfma32(k0, qf[db], s0);
      s1 = mfma32(k1, qf[db], s1);
    }
    __builtin_amdgcn_s_setprio(0);

    float tmax = fmaxf(s0[0], s1[0]);
#pragma unroll
    for (int i = 1; i < 16; ++i) tmax = fmaxf(tmax, fmaxf(s0[i], s1[i]));
    tmax = fmaxf(tmax, __shfl_xor(tmax, 32));
    if (__any(tmax > m_run + 62.0f)) {
      float mnew = fmaxf(m_run, tmax);
      float fac = exp2f((m_run - mnew) * CEXP);
      m_run = mnew;
      lacc *= fac;
#pragma unroll
      for (int r = 0; r < 16; ++r) {
        float fr = __shfl(fac, (r & 3) + 8 * (r >> 2) + 4 * h);
#pragma unroll
        for (int nf = 0; nf < 4; ++nf) oacc[nf][r] *= fr;
      }
    }
    const float mc = m_run * CEXP;
#pragma unroll
    for (int i = 0; i < 16; ++i) s0[i] = exp2f(fmaf(s0[i], CEXP, -mc));
#pragma unroll
    for (int i = 0; i < 16; ++i) s1[i] = exp2f(fmaf(s1[i], CEXP, -mc));
    float a0 = 0.f, a1 = 0.f, a2 = 0.f, a3 = 0.f;
#pragma unroll
    for (int i = 0; i < 16; i += 4) {
      a0 += s0[i] + s1[i];         a1 += s0[i + 1] + s1[i + 1];
      a2 += s0[i + 2] + s1[i + 2]; a3 += s0[i + 3] + s1[i + 3];
    }
    lacc += (a0 + a1) + (a2 + a3);

    __builtin_amdgcn_s_setprio(1);
    {
      bf16x8 pf = build_pf<0>(s0, h);
#pragma unroll
      for (int nf = 0; nf < 4; ++nf) {
        bf16x8 vf = *(const bf16x8*)(vb + (nf * 32 + l31) * 128 + (((0 + h) ^ swv[nf]) << 4));
        oacc[nf] = mfma32(pf, vf, oacc[nf]);
      }
    }
    {
      bf16x8 pf = build_pf<8>(s0, h);
#pragma unroll
      for (int nf = 0; nf < 4; ++nf) {
        bf16x8 vf = *(const bf16x8*)(vb + (nf * 32 + l31) * 128 + (((2 + h) ^ swv[nf]) << 4));
        oacc[nf] = mfma32(pf, vf, oacc[nf]);
      }
    }
    {
      bf16x8 pf = build_pf<0>(s1, h);
#pragma unroll
      for (int nf = 0; nf < 4; ++nf) {
        bf16x8 vf = *(const bf16x8*)(vb + (nf * 32 + l31) * 128 + (((4 + h) ^ swv[nf]) << 4));
        oacc[nf] = mfma32(pf, vf, oacc[nf]);
      }
    }
    {
      bf16x8 pf = build_pf<8>(s1, h);
#pragma unroll
      for (int nf = 0; nf < 4; ++nf) {
        bf16x8 vf = *(const bf16x8*)(vb + (nf * 32 + l31) * 128 + (((6 + h) ^ swv[nf]) << 4));
        oacc[nf] = mfma32(pf, vf, oacc[nf]);
      }
    }
    __builtin_amdgcn_s_setprio(0);

    __builtin_amdgcn_s_barrier();
    stage((t + 2) & (NT - 1), (t & 1) * 32768);
  }
  asm volatile("s_waitcnt vmcnt(0)" ::: "memory");

  lacc += __shfl_xor(lacc, 32);
  if (SPLIT == 1) {
    const float inv = 1.0f / lacc;
    float* ob = out + (size_t)(b * 4096 + qbase) * 128;
#pragma unroll
    for (int r = 0; r < 16; ++r) {
      const int rowD = (r & 3) + 8 * (r >> 2) + 4 * h;
      float ir = __shfl(inv, rowD);
#pragma unroll
      for (int nf = 0; nf < 4; ++nf)
        ob[(size_t)rowD * 128 + nf * 32 + l31] = oacc[nf][r] * ir;
    }
  } else {
    const int pb = s * 256 + b * 32 + qt;
    if (lane < 32) {
      Mpart[pb * 128 + w * 32 + l31] = m_run;
      Lpart[pb * 128 + w * 32 + l31] = lacc;
    }
    float* ob = Opart + ((size_t)pb * 128 + w * 32) * 128;
#pragma unroll
    for (int r = 0; r < 16; ++r) {
      const int rowD = (r & 3) + 8 * (r >> 2) + 4 * h;
#pragma unroll
      for (int nf = 0; nf < 4; ++nf)
        ob[(size_t)rowD * 128 + nf * 32 + l31] = oacc[nf][r];
    }
  }
}

// Combine 2 split partials. grid 4096 x 256: 8 rows/block, 32 lanes/row (float4).
__global__ __launch_bounds__(256) void combine_kernel(
    const float* __restrict__ Opart, const float* __restrict__ Mpart,
    const float* __restrict__ Lpart, float* __restrict__ out) {
  const int g = blockIdx.x * 8 + (threadIdx.x >> 5);
  const int lane32 = threadIdx.x & 31;
  const int b = g >> 12;
  const int pos = g & 4095;
  const int qt = pos >> 7;
  const int row = pos & 127;
  const int i0 = (b * 32 + qt) * 128 + row;
  const int i1 = (256 + b * 32 + qt) * 128 + row;
  const float m0 = Mpart[i0], m1 = Mpart[i1];
  const float l0 = Lpart[i0], l1 = Lpart[i1];
  const float m = fmaxf(m0, m1);
  const float w0 = exp2f((m0 - m) * CEXP_CONST);
  const float w1 = exp2f((m1 - m) * CEXP_CONST);
  const float inv = 1.0f / (w0 * l0 + w1 * l1);
  const float4 o0 = *(const float4*)(Opart + (size_t)i0 * 128 + lane32 * 4);
  const float4 o1 = *(const float4*)(Opart + (size_t)i1 * 128 + lane32 * 4);
  float4 o;
  o.x = (w0 * o0.x + w1 * o1.x) * inv;
  o.y = (w0 * o0.y + w1 * o1.y) * inv;
  o.z = (w0 * o0.z + w1 * o1.z) * inv;
  o.w = (w0 * o0.w + w1 * o1.w) * inv;
  *(float4*)(out + (size_t)g * 128 + lane32 * 4) = o;
}

extern "C" void kernel_launch(void* const* d_in, const int* in_sizes, int n_in,
                              void* d_out, int out_size, void* d_ws, size_t ws_size,
                              hipStream_t stream) {
  const float* q  = (const float*)d_in[0];
  const float* k  = (const float*)d_in[1];
  const float* v  = (const float*)d_in[2];
  const float* Wq = (const float*)d_in[3];
  const float* Wk = (const float*)d_in[4];
  const float* Wv = (const float*)d_in[5];
  float* out = (float*)d_out;
  char* ws = (char*)d_ws;
  bf16_t* Wt2 = (bf16_t*)(ws);
  bf16_t* Qp = (bf16_t*)(ws + (size_t)(1u << 20));
  bf16_t* Kp = (bf16_t*)(ws + (size_t)(9u << 20));
  bf16_t* Vt = (bf16_t*)(ws + (size_t)(17u << 20));
  float* Opart = (float*)(ws + (size_t)(32u << 20));
  float* Mpart = (float*)(ws + (size_t)(64u << 20));
  float* Lpart = (float*)(ws + (size_t)(64u << 20) + (256u << 10));

  hipLaunchKernelGGL(wt_kernel, dim3(1536), dim3(256), 0, stream, Wq, Wk, Wv, Wt2);
  hipLaunchKernelGGL(proj_kernel, dim3(1024, 3), dim3(256), 0, stream, q, k, v, Wt2, Qp, Kp, Vt);

  if (ws_size >= ((size_t)65 << 20)) {
    hipLaunchKernelGGL((attn_kernel<2>), dim3(512), dim3(256), 0, stream,
                       Qp, Kp, Vt, out, Opart, Mpart, Lpart);
    hipLaunchKernelGGL(combine_kernel, dim3(4096), dim3(256), 0, stream,
                       Opart, Mpart, Lpart, out);
  } else {
    hipLaunchKernelGGL((attn_kernel<1>), dim3(256), dim3(256), 0, stream,
                       Qp, Kp, Vt, out, Opart, Mpart, Lpart);
  }
}